// Round 2
// baseline (352.143 us; speedup 1.0000x reference)
//
#include <hip/hip_runtime.h>
#include <math.h>

// DTM layer: B=32, N=1024, D=2, M0=0.05, R=2
// out[b,n] = sqrt( (A_strict(t) + t*(wb - S_strict(t))) / wb )
// with t = tight upper bracket of the weighted quantile t* = inf{t : W(t) >= wb},
// wb = 0.05 * sum_b(w). t found by 2-level radix select (6 bits/pass) on the
// uint bit pattern of d2 (monotone for d2 >= 0), via per-wave LDS histograms.

constexpr int   N_GRID    = 1024;
constexpr int   PER_LANE  = 16;            // 1024 / 64
constexpr float M0_       = 0.05f;
constexpr unsigned BASE_BITS = 0x3A800000u;  // bits(2^-10); 64 buckets of 2^21 cover [2^-10, 2^6)
constexpr int   SH_A      = 21;            // pass A bucket width: quarter octave
constexpr int   SH_B      = 15;            // pass B refines to 2^15-wide bit bracket (rel ~2^-8)

__device__ __forceinline__ float wave_sum(float v) {
    #pragma unroll
    for (int off = 32; off > 0; off >>= 1)
        v += __shfl_xor(v, off, 64);
    return v;                              // all 64 lanes hold the total
}

__device__ __forceinline__ float wave_incl_scan(float v, int lane) {
    #pragma unroll
    for (int off = 1; off < 64; off <<= 1) {
        float t = __shfl_up(v, off, 64);
        if (lane >= off) v += t;
    }
    return v;
}

__global__ __launch_bounds__(256) void dtm_kernel(
    const float* __restrict__ input,   // [B, N, 2]
    const float* __restrict__ weight,  // [B, N]
    const float* __restrict__ grid,    // [N, 2]
    float* __restrict__ out)           // [B, N]
{
    __shared__ float hist[4][96];      // per-wave: 64 real buckets + 32 dummy slots
    const int wave = threadIdx.x >> 6;
    const int lane = threadIdx.x & 63;
    const int q    = (blockIdx.x << 2) + wave;
    const int b    = q >> 10;

    const float2 xq   = reinterpret_cast<const float2*>(input)[q];
    const float2* g2  = reinterpret_cast<const float2*>(grid);
    const float* wrow = weight + b * N_GRID;
    float* h = hist[wave];

    // cache this lane's 16 (d2, w) pairs in registers; coalesced loads
    float d2[PER_LANE], w[PER_LANE];
    float wsum = 0.f;
    #pragma unroll
    for (int k = 0; k < PER_LANE; ++k) {
        const int j = lane + (k << 6);
        const float2 g = g2[j];
        const float wj = wrow[j];
        const float dx = xq.x - g.x;
        const float dy = xq.y - g.y;
        d2[k] = dx * dx + dy * dy;
        w[k]  = wj;
        wsum += wj;
    }
    const float wb = M0_ * wave_sum(wsum);

    // ---- pass A: 64-bucket histogram over bit pattern (quarter-octave buckets)
    h[lane] = 0.f;                                   // zero own bucket (per-wave, in-order DS)
    #pragma unroll
    for (int k = 0; k < PER_LANE; ++k) {
        int ia = ((int)(__float_as_uint(d2[k]) - BASE_BITS)) >> SH_A;  // arithmetic shift
        ia = min(max(ia, 0), 63);                    // v_med3_i32 clamp
        atomicAdd(&h[ia], w[k]);
    }
    float cum = wave_incl_scan(h[lane], lane);
    unsigned long long m = __ballot(cum >= wb);
    int sA = (int)__ffsll(m) - 1;
    if (sA < 0) sA = 63;                             // unreachable guard
    const float below = (sA > 0)
        ? __uint_as_float(__builtin_amdgcn_readlane(__float_as_uint(cum), sA - 1))
        : 0.f;
    const float rA = wb - below;                     // remaining mass inside bucket sA (> 0)
    const unsigned bloA = BASE_BITS + ((unsigned)sA << SH_A);

    // ---- pass B: refine 6 more bits inside [bloA, bloA + 2^21)
    h[lane] = 0.f;
    const int dummy = 64 + (lane & 31);              // out-of-bracket sink (never read)
    #pragma unroll
    for (int k = 0; k < PER_LANE; ++k) {
        const unsigned u = __float_as_uint(d2[k]) - bloA;   // wraps for below-bracket
        const int idx = (u < (1u << SH_A)) ? (int)(u >> SH_B) : dummy;
        atomicAdd(&h[idx], w[k]);
    }
    cum = wave_incl_scan(h[lane], lane);
    m = __ballot(cum >= rA);                         // guaranteed nonzero: in-bracket mass >= rA
    int sB = (int)__ffsll(m) - 1;
    if (sB < 0) sB = 63;                             // unreachable guard
    const float t = __uint_as_float(bloA + (((unsigned)sB + 1u) << SH_B)); // W(t) >= wb

    // ---- final: strict sums at t, partial-weight interpolation
    float A = 0.f, S = 0.f;
    #pragma unroll
    for (int k = 0; k < PER_LANE; ++k) {
        const bool in = (d2[k] < t);
        A += in ? d2[k] * w[k] : 0.f;
        S += in ? w[k] : 0.f;
    }
    A = wave_sum(A);
    S = wave_sum(S);

    if (lane == 0) out[q] = sqrtf((A + t * (wb - S)) / wb);
}

extern "C" void kernel_launch(void* const* d_in, const int* in_sizes, int n_in,
                              void* d_out, int out_size, void* d_ws, size_t ws_size,
                              hipStream_t stream) {
    const float* input  = (const float*)d_in[0];   // [32,1024,2]
    const float* weight = (const float*)d_in[1];   // [32,1024]
    const float* grid   = (const float*)d_in[2];   // [1024,2]
    float* out = (float*)d_out;                    // [32,1024]

    const int total_q = 32 * 1024;                 // B*N
    dim3 blk(256);                                 // 4 waves/block, 1 query/wave
    dim3 grd(total_q / 4);                         // 8192 blocks
    hipLaunchKernelGGL(dtm_kernel, grd, blk, 0, stream,
                       input, weight, grid, out);
}

// Round 3
// 70.848 us; speedup vs baseline: 4.9704x; 4.9704x over previous
//
#include <hip/hip_runtime.h>
#include <math.h>

// DTM layer: B=32, N=1024, D=2, M0=0.05, R=2
// out[b,n] = sqrt( (A_strict(t) + t*(wb - S_strict(t))) / wb ),
//   t = tight upper bracket of weighted quantile t* = inf{u : W(u) >= wb},
//   W(u) = sum_{d2 <= u} w,  wb = 0.05 * sum_b(w).
// Bracket found by Illinois-safeguarded regula falsi on t (W(t) is ~linear in
// t for 2D clouds, so interpolation converges in ~5-9 evals vs 30 bisections).
// Error bound: val uses t=hi >= t*;  |dval| = (t-t*)(S_strict(t)-wb)/wb
//              <= 2e-4*hi*O(1)/wb  << fp32 noise  << 5.4e-2 threshold.

constexpr int   N_GRID   = 1024;
constexpr int   PER_LANE = 16;     // 1024 / 64
constexpr float M0_      = 0.05f;

__device__ __forceinline__ float wave_sum(float v) {
    #pragma unroll
    for (int off = 32; off > 0; off >>= 1)
        v += __shfl_xor(v, off, 64);
    return v;                      // all 64 lanes hold the total
}

__device__ __forceinline__ float wave_max(float v) {
    #pragma unroll
    for (int off = 32; off > 0; off >>= 1)
        v = fmaxf(v, __shfl_xor(v, off, 64));
    return v;
}

__global__ __launch_bounds__(256) void dtm_kernel(
    const float* __restrict__ input,   // [B, N, 2]
    const float* __restrict__ weight,  // [B, N]
    const float* __restrict__ grid,    // [N, 2]
    float* __restrict__ out)           // [B, N]
{
    const int wave = threadIdx.x >> 6;
    const int lane = threadIdx.x & 63;
    const int q    = (blockIdx.x << 2) + wave;      // query index
    const int b    = q >> 10;

    const float2 xq   = reinterpret_cast<const float2*>(input)[q];
    const float2* g2  = reinterpret_cast<const float2*>(grid);
    const float* wrow = weight + b * N_GRID;

    // cache this lane's 16 (d2, w) pairs in registers; coalesced loads
    float d2[PER_LANE], w[PER_LANE];
    float wsum = 0.f;
    float mx   = 0.f;
    #pragma unroll
    for (int k = 0; k < PER_LANE; ++k) {
        const int j = lane + (k << 6);
        const float2 g = g2[j];
        const float wj = wrow[j];
        const float dx = xq.x - g.x;
        const float dy = xq.y - g.y;
        d2[k] = dx * dx + dy * dy;
        w[k]  = wj;
        wsum += wj;
        mx    = fmaxf(mx, d2[k]);
    }
    const float total = wave_sum(wsum);
    const float wb    = M0_ * total;
    mx = wave_max(mx);

    // ---- Illinois regula falsi for t* on [0, mx]; invariant Wlo < wb <= Whi
    float lo = 0.f, Wlo = 0.f;
    float hi = mx,  Whi = total;
    int side = 0;
    #pragma unroll 1
    for (int it = 0; it < 20; ++it) {
        if (hi - lo <= 2e-4f * hi + 1e-8f) break;   // wave-uniform exit
        float frac = (wb - Wlo) / (Whi - Wlo);
        frac = fminf(fmaxf(frac, 0.10f), 0.90f);    // guarantee interval shrink
        const float t = lo + (hi - lo) * frac;
        float s = 0.f;
        #pragma unroll
        for (int k = 0; k < PER_LANE; ++k)
            s += (d2[k] <= t) ? w[k] : 0.f;
        s = wave_sum(s);
        if (s >= wb) {
            if (side == 1) Wlo = wb - 0.5f * (wb - Wlo);   // Illinois: decay stale side
            hi = t; Whi = s; side = 1;
        } else {
            if (side == -1) Whi = wb + 0.5f * (Whi - wb);
            lo = t; Wlo = s; side = -1;
        }
    }
    const float t = hi;                             // W(t) >= wb, t >= t*

    // ---- final: strict sums at t, partial-weight interpolation
    float A = 0.f, S = 0.f;
    #pragma unroll
    for (int k = 0; k < PER_LANE; ++k) {
        const bool in = (d2[k] < t);
        A += in ? d2[k] * w[k] : 0.f;
        S += in ? w[k] : 0.f;
    }
    A = wave_sum(A);
    S = wave_sum(S);

    if (lane == 0) out[q] = sqrtf((A + t * (wb - S)) / wb);
}

extern "C" void kernel_launch(void* const* d_in, const int* in_sizes, int n_in,
                              void* d_out, int out_size, void* d_ws, size_t ws_size,
                              hipStream_t stream) {
    const float* input  = (const float*)d_in[0];   // [32,1024,2]
    const float* weight = (const float*)d_in[1];   // [32,1024]
    const float* grid   = (const float*)d_in[2];   // [1024,2]
    float* out = (float*)d_out;                    // [32,1024]

    const int total_q = 32 * 1024;                 // B*N
    dim3 blk(256);                                 // 4 waves/block, 1 query/wave
    dim3 grd(total_q / 4);                         // 8192 blocks
    hipLaunchKernelGGL(dtm_kernel, grd, blk, 0, stream,
                       input, weight, grid, out);
}

// Round 4
// 47.634 us; speedup vs baseline: 7.3926x; 1.4873x over previous
//
#include <hip/hip_runtime.h>
#include <math.h>

// DTM layer: B=32, N=1024, D=2, M0=0.05, R=2
// out[b,n] = sqrt( (A_strict(t) + t*(wb - S_strict(t))) / wb ),
//   t = upper bracket of weighted quantile t* = inf{u : W(u) >= wb},
//   W(u) = sum_{d2 <= u} w,  wb = 0.05 * sum_b(w).
// Illinois regula falsi on t. Exact-formula error for t=hi >= t* is
//   val(t*) - val(hi) <= (hi-lo)*(Whi-wb)/wb   (computable!),
// so we exit when that bound <= 2e-3*hi -> output error ~1e-3 << 5.4e-2.

constexpr int   N_GRID   = 1024;
constexpr int   PER_LANE = 16;     // 1024 / 64
constexpr float M0_      = 0.05f;

__device__ __forceinline__ float wave_sum(float v) {
    #pragma unroll
    for (int off = 32; off > 0; off >>= 1)
        v += __shfl_xor(v, off, 64);
    return v;                      // all 64 lanes hold the total
}

__device__ __forceinline__ float wave_max(float v) {
    #pragma unroll
    for (int off = 32; off > 0; off >>= 1)
        v = fmaxf(v, __shfl_xor(v, off, 64));
    return v;
}

__global__ __launch_bounds__(256) void dtm_kernel(
    const float* __restrict__ input,   // [B, N, 2]
    const float* __restrict__ weight,  // [B, N]
    const float* __restrict__ grid,    // [N, 2]
    float* __restrict__ out)           // [B, N]
{
    const int wave = threadIdx.x >> 6;
    const int lane = threadIdx.x & 63;
    const int q    = (blockIdx.x << 2) + wave;      // query index
    const int b    = q >> 10;

    const float2 xq = reinterpret_cast<const float2*>(input)[q];

    // blocked ownership: lane owns grid points [lane*16, lane*16+16)
    // -> 16B/lane fully-coalesced float4 loads (reductions are order-invariant)
    const int base = lane * PER_LANE;
    const float4* w4 = reinterpret_cast<const float4*>(weight + b * N_GRID + base);
    const float4* g4 = reinterpret_cast<const float4*>(grid + 2 * base);

    float4 wv[4], gv[8];
    #pragma unroll
    for (int i = 0; i < 4; ++i) wv[i] = w4[i];
    #pragma unroll
    for (int i = 0; i < 8; ++i) gv[i] = g4[i];

    float d2[PER_LANE], w[PER_LANE];
    float wsum = 0.f, mx = 0.f;
    #pragma unroll
    for (int i = 0; i < 8; ++i) {                   // 2 points per float4
        float dx0 = xq.x - gv[i].x, dy0 = xq.y - gv[i].y;
        float dx1 = xq.x - gv[i].z, dy1 = xq.y - gv[i].w;
        d2[2*i]   = dx0 * dx0 + dy0 * dy0;
        d2[2*i+1] = dx1 * dx1 + dy1 * dy1;
        mx = fmaxf(mx, fmaxf(d2[2*i], d2[2*i+1]));
    }
    #pragma unroll
    for (int i = 0; i < 4; ++i) {
        w[4*i+0] = wv[i].x; w[4*i+1] = wv[i].y;
        w[4*i+2] = wv[i].z; w[4*i+3] = wv[i].w;
        wsum += wv[i].x + wv[i].y + wv[i].z + wv[i].w;
    }
    const float total = wave_sum(wsum);
    const float wb    = M0_ * total;
    mx = wave_max(mx);

    // ---- Illinois regula falsi; invariant Wlo < wb <= Whi on [lo, hi]
    float lo = 0.f, Wlo = 0.f;
    float hi = mx,  Whi = total;
    int side = 0;
    #pragma unroll 1
    for (int it = 0; it < 16; ++it) {
        // principled exit: val-error bound (hi-lo)*(Whi-wb)/wb <= 2e-3*hi
        if ((hi - lo) * (Whi - wb) <= 2e-3f * wb * hi + 1e-12f) break;
        if (hi - lo <= 1e-4f * hi) break;
        float frac = (wb - Wlo) / (Whi - Wlo);
        frac = fminf(fmaxf(frac, 0.04f), 0.96f);
        const float t = lo + (hi - lo) * frac;
        float s = 0.f;
        #pragma unroll
        for (int k = 0; k < PER_LANE; ++k)
            s += (d2[k] <= t) ? w[k] : 0.f;
        s = wave_sum(s);
        if (s >= wb) {
            if (side == 1) Wlo = wb - 0.5f * (wb - Wlo);   // Illinois decay
            hi = t; Whi = s; side = 1;
        } else {
            if (side == -1) Whi = wb + 0.5f * (Whi - wb);
            lo = t; Wlo = s; side = -1;
        }
    }
    const float t = hi;                             // W(t) >= wb, t >= t*

    // ---- final: strict sums at t, partial-weight interpolation (exact form)
    float A = 0.f, S = 0.f;
    #pragma unroll
    for (int k = 0; k < PER_LANE; ++k) {
        const bool in = (d2[k] < t);
        A += in ? d2[k] * w[k] : 0.f;
        S += in ? w[k] : 0.f;
    }
    A = wave_sum(A);
    S = wave_sum(S);

    if (lane == 0) out[q] = sqrtf(fmaxf((A + t * (wb - S)) / wb, 0.f));
}

extern "C" void kernel_launch(void* const* d_in, const int* in_sizes, int n_in,
                              void* d_out, int out_size, void* d_ws, size_t ws_size,
                              hipStream_t stream) {
    const float* input  = (const float*)d_in[0];   // [32,1024,2]
    const float* weight = (const float*)d_in[1];   // [32,1024]
    const float* grid   = (const float*)d_in[2];   // [1024,2]
    float* out = (float*)d_out;                    // [32,1024]

    const int total_q = 32 * 1024;                 // B*N
    dim3 blk(256);                                 // 4 waves/block, 1 query/wave
    dim3 grd(total_q / 4);                         // 8192 blocks
    hipLaunchKernelGGL(dtm_kernel, grd, blk, 0, stream,
                       input, weight, grid, out);
}

// Round 5
// 46.015 us; speedup vs baseline: 7.6527x; 1.0352x over previous
//
#include <hip/hip_runtime.h>
#include <math.h>

// DTM layer: B=32, N=1024, D=2, M0=0.05, R=2
// out[b,n] = sqrt( (A_strict(t) + t*(wb - S_strict(t))) / wb ),
//   t = upper bracket of weighted quantile t* = inf{u : W(u) >= wb},
//   W(u) = sum_{d2 <= u} w,  wb = 0.05 * sum_b(w).
// Illinois regula falsi on t; exit when computable val-error bound
// (hi-lo)*(Whi-wb)/wb <= 2e-3*hi (output err ~1e-3 << 5.4e-2 threshold).
// All wave reductions via DPP (row_shr + row_bcast, VALU pipe) instead of
// ds_swizzle butterflies -> ~7x shorter serial chain per reduction, and the
// readlane(63) result is an SGPR so the bisection state is wave-uniform
// scalar (SALU control flow).

constexpr int   N_GRID   = 1024;
constexpr int   PER_LANE = 16;     // 1024 / 64
constexpr float M0_      = 0.05f;

template<int CTRL, int RM>
__device__ __forceinline__ float dpp_fadd(float v) {
    int moved = __builtin_amdgcn_update_dpp(0, __float_as_int(v), CTRL, RM, 0xF, true);
    return v + __int_as_float(moved);
}
template<int CTRL, int RM>
__device__ __forceinline__ float dpp_fmax(float v) {
    int moved = __builtin_amdgcn_update_dpp(0, __float_as_int(v), CTRL, RM, 0xF, true);
    return fmaxf(v, __int_as_float(moved));
}

// full-wave sum; returns wave-uniform (SGPR) total
__device__ __forceinline__ float wave_sum_u(float v) {
    v = dpp_fadd<0x111, 0xF>(v);   // row_shr:1
    v = dpp_fadd<0x112, 0xF>(v);   // row_shr:2
    v = dpp_fadd<0x114, 0xF>(v);   // row_shr:4
    v = dpp_fadd<0x118, 0xF>(v);   // row_shr:8  -> lane 15/31/47/63 hold row sums
    v = dpp_fadd<0x142, 0xA>(v);   // row_bcast:15 -> lane31 = r0+r1, lane63 = r2+r3
    v = dpp_fadd<0x143, 0xC>(v);   // row_bcast:31 -> lane63 = total
    return __uint_as_float((unsigned)__builtin_amdgcn_readlane(__float_as_int(v), 63));
}
__device__ __forceinline__ float wave_max_u(float v) {   // v >= 0 required
    v = dpp_fmax<0x111, 0xF>(v);
    v = dpp_fmax<0x112, 0xF>(v);
    v = dpp_fmax<0x114, 0xF>(v);
    v = dpp_fmax<0x118, 0xF>(v);
    v = dpp_fmax<0x142, 0xA>(v);
    v = dpp_fmax<0x143, 0xC>(v);
    return __uint_as_float((unsigned)__builtin_amdgcn_readlane(__float_as_int(v), 63));
}

__global__ __launch_bounds__(256) void dtm_kernel(
    const float* __restrict__ input,   // [B, N, 2]
    const float* __restrict__ weight,  // [B, N]
    const float* __restrict__ grid,    // [N, 2]
    float* __restrict__ out)           // [B, N]
{
    const int wave = threadIdx.x >> 6;
    const int lane = threadIdx.x & 63;
    const int q    = (blockIdx.x << 2) + wave;      // query index
    const int b    = q >> 10;

    const float2 xq = reinterpret_cast<const float2*>(input)[q];

    // blocked ownership: lane owns grid points [lane*16, lane*16+16)
    // -> fully-coalesced float4 loads (reductions are order-invariant)
    const int base = lane * PER_LANE;
    const float4* w4 = reinterpret_cast<const float4*>(weight + b * N_GRID + base);
    const float4* g4 = reinterpret_cast<const float4*>(grid + 2 * base);

    float4 wv[4], gv[8];
    #pragma unroll
    for (int i = 0; i < 4; ++i) wv[i] = w4[i];
    #pragma unroll
    for (int i = 0; i < 8; ++i) gv[i] = g4[i];

    float d2[PER_LANE], w[PER_LANE];
    float wsum = 0.f, mx = 0.f;
    #pragma unroll
    for (int i = 0; i < 8; ++i) {                   // 2 points per float4
        float dx0 = xq.x - gv[i].x, dy0 = xq.y - gv[i].y;
        float dx1 = xq.x - gv[i].z, dy1 = xq.y - gv[i].w;
        d2[2*i]   = dx0 * dx0 + dy0 * dy0;
        d2[2*i+1] = dx1 * dx1 + dy1 * dy1;
        mx = fmaxf(mx, fmaxf(d2[2*i], d2[2*i+1]));
    }
    #pragma unroll
    for (int i = 0; i < 4; ++i) {
        w[4*i+0] = wv[i].x; w[4*i+1] = wv[i].y;
        w[4*i+2] = wv[i].z; w[4*i+3] = wv[i].w;
        wsum += wv[i].x + wv[i].y + wv[i].z + wv[i].w;
    }
    const float total = wave_sum_u(wsum);           // uniform
    const float wb    = M0_ * total;
    mx = wave_max_u(mx);                            // uniform

    // ---- Illinois regula falsi; invariant Wlo < wb <= Whi on [lo, hi]
    float lo = 0.f, Wlo = 0.f;
    float hi = mx,  Whi = total;
    int side = 0;
    #pragma unroll 1
    for (int it = 0; it < 16; ++it) {
        // principled exit: val-error bound (hi-lo)*(Whi-wb)/wb <= 2e-3*hi
        if ((hi - lo) * (Whi - wb) <= 2e-3f * wb * hi + 1e-12f) break;
        if (hi - lo <= 1e-4f * hi) break;
        float frac = (wb - Wlo) / (Whi - Wlo);
        frac = fminf(fmaxf(frac, 0.04f), 0.96f);
        const float t = lo + (hi - lo) * frac;      // uniform
        float sv = 0.f;
        #pragma unroll
        for (int k = 0; k < PER_LANE; ++k)
            sv += (d2[k] <= t) ? w[k] : 0.f;
        const float s = wave_sum_u(sv);             // uniform
        if (s >= wb) {
            if (side == 1) Wlo = wb - 0.5f * (wb - Wlo);   // Illinois decay
            hi = t; Whi = s; side = 1;
        } else {
            if (side == -1) Whi = wb + 0.5f * (Whi - wb);
            lo = t; Wlo = s; side = -1;
        }
    }
    const float t = hi;                             // W(t) >= wb, t >= t*

    // ---- final: strict sums at t, partial-weight interpolation (exact form)
    float Av = 0.f, Sv = 0.f;
    #pragma unroll
    for (int k = 0; k < PER_LANE; ++k) {
        const bool in = (d2[k] < t);
        Av += in ? d2[k] * w[k] : 0.f;
        Sv += in ? w[k] : 0.f;
    }
    const float A = wave_sum_u(Av);
    const float S = wave_sum_u(Sv);

    if (lane == 0) out[q] = sqrtf(fmaxf((A + t * (wb - S)) / wb, 0.f));
}

extern "C" void kernel_launch(void* const* d_in, const int* in_sizes, int n_in,
                              void* d_out, int out_size, void* d_ws, size_t ws_size,
                              hipStream_t stream) {
    const float* input  = (const float*)d_in[0];   // [32,1024,2]
    const float* weight = (const float*)d_in[1];   // [32,1024]
    const float* grid   = (const float*)d_in[2];   // [1024,2]
    float* out = (float*)d_out;                    // [32,1024]

    const int total_q = 32 * 1024;                 // B*N
    dim3 blk(256);                                 // 4 waves/block, 1 query/wave
    dim3 grd(total_q / 4);                         // 8192 blocks
    hipLaunchKernelGGL(dtm_kernel, grd, blk, 0, stream,
                       input, weight, grid, out);
}

// Round 6
// 45.792 us; speedup vs baseline: 7.6901x; 1.0049x over previous
//
#include <hip/hip_runtime.h>
#include <math.h>

// DTM layer: B=32, N=1024, D=2, M0=0.05, R=2
// out[b,n] = sqrt( (A_strict(t) + t*(wb - S_strict(t))) / wb ),
//   t = upper bracket of weighted quantile t* = inf{u : W(u) >= wb},
//   W(u) = sum_{d2 <= u} w,  wb = 0.05 * sum_b(w).
// Illinois regula falsi on t; exit when computable val-error bound
// (hi-lo)*(Whi-wb)/wb <= 2e-3*hi (output err ~1e-3 << 5.4e-2 threshold).
// R5: __launch_bounds__(256,4) + opaque asm pins on d2[]/w[] force the
// arrays to stay VGPR-resident across the bisection loop (R4 showed
// VGPR_Count=32 -> compiler was rematerializing the 24 float4 loads +
// d2 recompute EVERY iteration to chase 8-wave occupancy).

constexpr int   N_GRID   = 1024;
constexpr int   PER_LANE = 16;     // 1024 / 64
constexpr float M0_      = 0.05f;

template<int CTRL, int RM>
__device__ __forceinline__ float dpp_fadd(float v) {
    int moved = __builtin_amdgcn_update_dpp(0, __float_as_int(v), CTRL, RM, 0xF, true);
    return v + __int_as_float(moved);
}
template<int CTRL, int RM>
__device__ __forceinline__ float dpp_fmax(float v) {
    int moved = __builtin_amdgcn_update_dpp(0, __float_as_int(v), CTRL, RM, 0xF, true);
    return fmaxf(v, __int_as_float(moved));
}

// full-wave sum; returns wave-uniform (SGPR) total
__device__ __forceinline__ float wave_sum_u(float v) {
    v = dpp_fadd<0x111, 0xF>(v);   // row_shr:1
    v = dpp_fadd<0x112, 0xF>(v);   // row_shr:2
    v = dpp_fadd<0x114, 0xF>(v);   // row_shr:4
    v = dpp_fadd<0x118, 0xF>(v);   // row_shr:8  -> lanes 15/31/47/63 hold row sums
    v = dpp_fadd<0x142, 0xA>(v);   // row_bcast:15
    v = dpp_fadd<0x143, 0xC>(v);   // row_bcast:31 -> lane63 = total
    return __uint_as_float((unsigned)__builtin_amdgcn_readlane(__float_as_int(v), 63));
}
__device__ __forceinline__ float wave_max_u(float v) {   // v >= 0 required
    v = dpp_fmax<0x111, 0xF>(v);
    v = dpp_fmax<0x112, 0xF>(v);
    v = dpp_fmax<0x114, 0xF>(v);
    v = dpp_fmax<0x118, 0xF>(v);
    v = dpp_fmax<0x142, 0xA>(v);
    v = dpp_fmax<0x143, 0xC>(v);
    return __uint_as_float((unsigned)__builtin_amdgcn_readlane(__float_as_int(v), 63));
}

__global__ __launch_bounds__(256, 4) void dtm_kernel(
    const float* __restrict__ input,   // [B, N, 2]
    const float* __restrict__ weight,  // [B, N]
    const float* __restrict__ grid,    // [N, 2]
    float* __restrict__ out)           // [B, N]
{
    const int wave = threadIdx.x >> 6;
    const int lane = threadIdx.x & 63;
    const int q    = (blockIdx.x << 2) + wave;      // query index
    const int b    = q >> 10;

    const float2 xq = reinterpret_cast<const float2*>(input)[q];

    // blocked ownership: lane owns grid points [lane*16, lane*16+16)
    const int base = lane * PER_LANE;
    const float4* w4 = reinterpret_cast<const float4*>(weight + b * N_GRID + base);
    const float4* g4 = reinterpret_cast<const float4*>(grid + 2 * base);

    float4 wv[4], gv[8];
    #pragma unroll
    for (int i = 0; i < 4; ++i) wv[i] = w4[i];
    #pragma unroll
    for (int i = 0; i < 8; ++i) gv[i] = g4[i];

    float d2[PER_LANE], w[PER_LANE];
    float wsum = 0.f, mx = 0.f;
    #pragma unroll
    for (int i = 0; i < 8; ++i) {                   // 2 points per float4
        float dx0 = xq.x - gv[i].x, dy0 = xq.y - gv[i].y;
        float dx1 = xq.x - gv[i].z, dy1 = xq.y - gv[i].w;
        d2[2*i]   = dx0 * dx0 + dy0 * dy0;
        d2[2*i+1] = dx1 * dx1 + dy1 * dy1;
        mx = fmaxf(mx, fmaxf(d2[2*i], d2[2*i+1]));
    }
    #pragma unroll
    for (int i = 0; i < 4; ++i) {
        w[4*i+0] = wv[i].x; w[4*i+1] = wv[i].y;
        w[4*i+2] = wv[i].z; w[4*i+3] = wv[i].w;
        wsum += wv[i].x + wv[i].y + wv[i].z + wv[i].w;
    }

    // pin the working set in VGPRs: opaque defs forbid rematerialization
    // (reload+recompute) of d2/w inside the bisection loop.
    asm volatile("" : "+v"(d2[0]), "+v"(d2[1]), "+v"(d2[2]),  "+v"(d2[3]),
                      "+v"(d2[4]), "+v"(d2[5]), "+v"(d2[6]),  "+v"(d2[7]),
                      "+v"(d2[8]), "+v"(d2[9]), "+v"(d2[10]), "+v"(d2[11]),
                      "+v"(d2[12]),"+v"(d2[13]),"+v"(d2[14]), "+v"(d2[15]));
    asm volatile("" : "+v"(w[0]),  "+v"(w[1]),  "+v"(w[2]),   "+v"(w[3]),
                      "+v"(w[4]),  "+v"(w[5]),  "+v"(w[6]),   "+v"(w[7]),
                      "+v"(w[8]),  "+v"(w[9]),  "+v"(w[10]),  "+v"(w[11]),
                      "+v"(w[12]), "+v"(w[13]), "+v"(w[14]),  "+v"(w[15]));

    const float total = wave_sum_u(wsum);           // uniform
    const float wb    = M0_ * total;
    mx = wave_max_u(mx);                            // uniform

    // ---- Illinois regula falsi; invariant Wlo < wb <= Whi on [lo, hi]
    float lo = 0.f, Wlo = 0.f;
    float hi = mx,  Whi = total;
    int side = 0;
    #pragma unroll 1
    for (int it = 0; it < 16; ++it) {
        // principled exit: val-error bound (hi-lo)*(Whi-wb)/wb <= 2e-3*hi
        if ((hi - lo) * (Whi - wb) <= 2e-3f * wb * hi + 1e-12f) break;
        if (hi - lo <= 1e-4f * hi) break;
        float frac = (wb - Wlo) / (Whi - Wlo);
        frac = fminf(fmaxf(frac, 0.04f), 0.96f);
        const float t = lo + (hi - lo) * frac;      // uniform
        float sv = 0.f;
        #pragma unroll
        for (int k = 0; k < PER_LANE; ++k)
            sv += (d2[k] <= t) ? w[k] : 0.f;
        const float s = wave_sum_u(sv);             // uniform
        if (s >= wb) {
            if (side == 1) Wlo = wb - 0.5f * (wb - Wlo);   // Illinois decay
            hi = t; Whi = s; side = 1;
        } else {
            if (side == -1) Whi = wb + 0.5f * (Whi - wb);
            lo = t; Wlo = s; side = -1;
        }
    }
    const float t = hi;                             // W(t) >= wb, t >= t*

    // ---- final: strict sums at t, partial-weight interpolation (exact form)
    float Av = 0.f, Sv = 0.f;
    #pragma unroll
    for (int k = 0; k < PER_LANE; ++k) {
        const bool in = (d2[k] < t);
        Av += in ? d2[k] * w[k] : 0.f;
        Sv += in ? w[k] : 0.f;
    }
    const float A = wave_sum_u(Av);
    const float S = wave_sum_u(Sv);

    if (lane == 0) out[q] = sqrtf(fmaxf((A + t * (wb - S)) / wb, 0.f));
}

extern "C" void kernel_launch(void* const* d_in, const int* in_sizes, int n_in,
                              void* d_out, int out_size, void* d_ws, size_t ws_size,
                              hipStream_t stream) {
    const float* input  = (const float*)d_in[0];   // [32,1024,2]
    const float* weight = (const float*)d_in[1];   // [32,1024]
    const float* grid   = (const float*)d_in[2];   // [1024,2]
    float* out = (float*)d_out;                    // [32,1024]

    const int total_q = 32 * 1024;                 // B*N
    dim3 blk(256);                                 // 4 waves/block, 1 query/wave
    dim3 grd(total_q / 4);                         // 8192 blocks
    hipLaunchKernelGGL(dtm_kernel, grd, blk, 0, stream,
                       input, weight, grid, out);
}